// Round 1
// baseline (459.884 us; speedup 1.0000x reference)
//
#include <hip/hip_runtime.h>
#include <hip/hip_bf16.h>

// FFTConv: y[b,d,:] = (h[d] * x[b,d])[0:L] (causal linear conv via FFT) + x[b,d]*B[d]
// d_model=1024, L=8192, batch=2, fp32. FFT length 2L=16384 in 128KB LDS.

#define L_SEQ   8192
#define N_FFT   16384
#define LOG2N   14
#define D_MODEL 1024
#define NTHREADS 1024
#define H_STRIDE 8208   // complex elems per channel row (>=8193, keeps 16B alignment)

__device__ __forceinline__ float2 cmul(float2 a, float2 b) {
    return make_float2(a.x * b.x - a.y * b.y, a.x * b.y + a.y * b.x);
}

__device__ __forceinline__ unsigned bitrev14(unsigned v) {
    return __brev(v) >> (32 - LOG2N);
}

// In-place DIF FFT over LDS array z[N_FFT]. SIGN = -1 forward, +1 inverse (unscaled).
template <int SIGN>
__device__ __forceinline__ void fft_dif(float2* z, int tid) {
    const float two_pi_over_n = SIGN * 6.28318530717958647692f * (1.0f / (float)N_FFT);
#pragma unroll
    for (int s = 0; s < LOG2N; ++s) {
        const int half = N_FFT >> (s + 1);
        for (int r = 0; r < (N_FFT / 2) / NTHREADS; ++r) {
            const int t = tid + r * NTHREADS;          // 0..8191 butterfly index
            const int j = t & (half - 1);
            const int i0 = ((t & ~(half - 1)) << 1) | j;
            const int i1 = i0 + half;
            const float ang = two_pi_over_n * (float)(j << s);
            float sv, cv;
            __sincosf(ang, &sv, &cv);
            const float2 w = make_float2(cv, sv);
            const float2 a = z[i0];
            const float2 b = z[i1];
            z[i0] = make_float2(a.x + b.x, a.y + b.y);
            z[i1] = cmul(make_float2(a.x - b.x, a.y - b.y), w);
        }
        __syncthreads();
    }
    // bit-reverse permute back to natural order (pairs disjoint; one owner per pair)
    for (int i = tid; i < N_FFT; i += NTHREADS) {
        const unsigned rv = bitrev14((unsigned)i);
        if (rv > (unsigned)i) {
            const float2 tmp = z[i];
            z[i] = z[rv];
            z[rv] = tmp;
        }
    }
    __syncthreads();
}

// Kernel 1: H[d, k] = FFT_16384(pad(h[d,:]))[k] / 16384, k = 0..8192 stored.
__global__ void __launch_bounds__(NTHREADS) fftconv_filter_kernel(
        const float* __restrict__ h, float2* __restrict__ H) {
    extern __shared__ float2 z[];
    const int d = blockIdx.x;
    const int tid = threadIdx.x;

    const float* hrow = h + (size_t)d * L_SEQ;
    for (int t = tid; t < L_SEQ; t += NTHREADS) {
        z[t] = make_float2(hrow[t], 0.0f);
        z[t + L_SEQ] = make_float2(0.0f, 0.0f);
    }
    __syncthreads();

    fft_dif<-1>(z, tid);

    const float invn = 1.0f / (float)N_FFT;
    float2* Hrow = H + (size_t)d * H_STRIDE;
    for (int k = tid; k <= L_SEQ; k += NTHREADS) {
        const float2 v = z[k];
        Hrow[k] = make_float2(v.x * invn, v.y * invn);
    }
}

// Kernel 2: per channel d, z = x[0,d]+i*x[1,d] padded; Y = IFFT(H_full .* FFT(z));
// y[0,d]=Re(Y)+x0*B, y[1,d]=Im(Y)+x1*B.
__global__ void __launch_bounds__(NTHREADS) fftconv_conv_kernel(
        const float* __restrict__ x, const float* __restrict__ Bg,
        const float2* __restrict__ H, float* __restrict__ y) {
    extern __shared__ float2 z[];
    const int d = blockIdx.x;
    const int tid = threadIdx.x;

    const float* x0 = x + (size_t)d * L_SEQ;                     // x[0,d,:]
    const float* x1 = x + (size_t)(D_MODEL + d) * L_SEQ;         // x[1,d,:]

    for (int t = tid; t < L_SEQ; t += NTHREADS) {
        z[t] = make_float2(x0[t], x1[t]);
        z[t + L_SEQ] = make_float2(0.0f, 0.0f);
    }
    __syncthreads();

    fft_dif<-1>(z, tid);

    // pointwise multiply with conjugate-symmetric expansion of H[d]
    const float2* Hrow = H + (size_t)d * H_STRIDE;
    for (int i = tid; i < N_FFT; i += NTHREADS) {
        float2 hk;
        if (i <= L_SEQ) {
            hk = Hrow[i];
        } else {
            const float2 t2 = Hrow[N_FFT - i];
            hk = make_float2(t2.x, -t2.y);
        }
        z[i] = cmul(z[i], hk);
    }
    __syncthreads();

    fft_dif<+1>(z, tid);   // unscaled inverse; 1/N folded into H

    const float Bd = Bg[d];
    float* y0 = y + (size_t)d * L_SEQ;
    float* y1 = y + (size_t)(D_MODEL + d) * L_SEQ;
    for (int t = tid; t < L_SEQ; t += NTHREADS) {
        const float2 v = z[t];
        y0[t] = v.x + x0[t] * Bd;
        y1[t] = v.y + x1[t] * Bd;
    }
}

extern "C" void kernel_launch(void* const* d_in, const int* in_sizes, int n_in,
                              void* d_out, int out_size, void* d_ws, size_t ws_size,
                              hipStream_t stream) {
    const float* h = (const float*)d_in[0];   // (1024, 8192)
    const float* x = (const float*)d_in[1];   // (2, 1024, 8192)
    const float* B = (const float*)d_in[2];   // (1024, 1)
    float* y = (float*)d_out;                 // (2, 1024, 8192)
    float2* H = (float2*)d_ws;                // 1024 x H_STRIDE complex = 67.2 MB

    const size_t lds_bytes = (size_t)N_FFT * sizeof(float2);  // 128 KB

    fftconv_filter_kernel<<<dim3(D_MODEL), dim3(NTHREADS), lds_bytes, stream>>>(h, H);
    fftconv_conv_kernel<<<dim3(D_MODEL), dim3(NTHREADS), lds_bytes, stream>>>(x, B, H, y);
}

// Round 2
// 302.198 us; speedup vs baseline: 1.5218x; 1.5218x over previous
//
#include <hip/hip_runtime.h>
#include <hip/hip_bf16.h>

// FFTConv fused: y[b,d,:] = (h[d] (*) x[b,d])[0:L] + x[b,d]*B[d]
// d_model=1024, L=8192, batch=2, fp32. One block per channel.
// Radix-4 DIF forward (digit-reversed output, no reorder), pointwise in
// permuted domain, stage-exact inverse (conj twiddles, reversed order) ->
// natural-order output. Batch packed as complex z = x0 + i*x1.

#define L_SEQ   8192
#define N_FFT   16384
#define D_MODEL 1024
#define NTH     1024

// XOR swizzle on float2 index: caps LDS bank conflicts at ~4-way for all
// power-of-2 strides, keeps stride-1 access conflict-free.
#define SWZ(i) ((i) ^ (((i) >> 4) & 15))

__device__ __forceinline__ float2 cmul(float2 a, float2 b) {
    return make_float2(a.x * b.x - a.y * b.y, a.x * b.y + a.y * b.x);
}

// One full 7-stage radix-4 pass. SIGN=-1: forward DIF (natural in, digit-rev out).
// SIGN=+1: exact inverse of the forward pass (digit-rev in, natural out),
// unscaled (factor N folded into the filter spectrum).
template <int SIGN>
__device__ __forceinline__ void fft_pass(float2* __restrict__ z, const int tid) {
#pragma unroll
    for (int si = 0; si < 7; ++si) {
        const int s  = (SIGN < 0) ? si : (6 - si);
        const int lq = 12 - 2 * s;       // log2(q)
        const int q  = 1 << lq;          // butterfly span
        const float fconst = (float)SIGN * 6.283185307179586f / (float)(1 << (lq + 2));
#pragma unroll
        for (int r = 0; r < 4; ++r) {
            const int t = tid + r * NTH;             // butterfly id 0..4095
            const int j = t & (q - 1);
            const int base = ((t >> lq) << (lq + 2)) | j;
            const int p0 = SWZ(base);
            const int p1 = SWZ(base + q);
            const int p2 = SWZ(base + 2 * q);
            const int p3 = SWZ(base + 3 * q);
            float sv, cv;
            __sincosf(fconst * (float)j, &sv, &cv);
            const float2 w1 = make_float2(cv, sv);
            const float2 w2 = cmul(w1, w1);
            const float2 w3 = cmul(w2, w1);
            if (SIGN < 0) {
                const float2 a0 = z[p0], a1 = z[p1], a2 = z[p2], a3 = z[p3];
                const float2 t0 = make_float2(a0.x + a2.x, a0.y + a2.y);
                const float2 t1 = make_float2(a0.x - a2.x, a0.y - a2.y);
                const float2 t2 = make_float2(a1.x + a3.x, a1.y + a3.y);
                const float2 t3 = make_float2(a1.x - a3.x, a1.y - a3.y);
                const float2 A0 = make_float2(t0.x + t2.x, t0.y + t2.y);
                const float2 A2 = make_float2(t0.x - t2.x, t0.y - t2.y);
                // A1 = t1 - i*t3 ; A3 = t1 + i*t3
                const float2 A1 = make_float2(t1.x + t3.y, t1.y - t3.x);
                const float2 A3 = make_float2(t1.x - t3.y, t1.y + t3.x);
                z[p0] = A0;
                z[p1] = cmul(A1, w1);
                z[p2] = cmul(A2, w2);
                z[p3] = cmul(A3, w3);
            } else {
                const float2 b0 = z[p0], b1 = z[p1], b2 = z[p2], b3 = z[p3];
                const float2 A0 = b0;
                const float2 A1 = cmul(b1, w1);   // w1 here = conj(forward w1)
                const float2 A2 = cmul(b2, w2);
                const float2 A3 = cmul(b3, w3);
                const float2 u0 = make_float2(A0.x + A2.x, A0.y + A2.y);
                const float2 u1 = make_float2(A0.x - A2.x, A0.y - A2.y);
                const float2 u2 = make_float2(A1.x + A3.x, A1.y + A3.y);
                const float2 u3 = make_float2(A1.x - A3.x, A1.y - A3.y);
                z[p0] = make_float2(u0.x + u2.x, u0.y + u2.y);
                z[p2] = make_float2(u0.x - u2.x, u0.y - u2.y);
                // a1 = u1 + i*u3 ; a3 = u1 - i*u3
                z[p1] = make_float2(u1.x - u3.y, u1.y + u3.x);
                z[p3] = make_float2(u1.x + u3.y, u1.y - u3.x);
            }
        }
        __syncthreads();
    }
}

__global__ void __launch_bounds__(NTH) fftconv_fused_kernel(
        const float* __restrict__ h, const float* __restrict__ x,
        const float* __restrict__ Bg, float* __restrict__ y) {
    extern __shared__ float2 z[];
    const int d = blockIdx.x;
    const int tid = threadIdx.x;

    // ---- FFT of filter row ----
    const float* hrow = h + (size_t)d * L_SEQ;
#pragma unroll
    for (int r = 0; r < 8; ++r) {
        const int t = tid + r * NTH;
        z[SWZ(t)]         = make_float2(hrow[t], 0.0f);
        z[SWZ(t + L_SEQ)] = make_float2(0.0f, 0.0f);
    }
    __syncthreads();
    fft_pass<-1>(z, tid);

    // hold H/N in registers (pointwise slots: raw physical indices)
    float2 Hreg[16];
    const float invn = 1.0f / (float)N_FFT;
#pragma unroll
    for (int r = 0; r < 16; ++r) {
        const float2 v = z[tid + r * NTH];
        Hreg[r] = make_float2(v.x * invn, v.y * invn);
    }
    __syncthreads();   // everyone done reading H before z is overwritten

    // ---- FFT of batch-packed signal z = x0 + i*x1 ----
    const float* x0 = x + (size_t)d * L_SEQ;
    const float* x1 = x + (size_t)(D_MODEL + d) * L_SEQ;
#pragma unroll
    for (int r = 0; r < 8; ++r) {
        const int t = tid + r * NTH;
        z[SWZ(t)]         = make_float2(x0[t], x1[t]);
        z[SWZ(t + L_SEQ)] = make_float2(0.0f, 0.0f);
    }
    __syncthreads();
    fft_pass<-1>(z, tid);

    // pointwise multiply in the (common) permuted spectral domain
#pragma unroll
    for (int r = 0; r < 16; ++r) {
        const int i = tid + r * NTH;
        z[i] = cmul(z[i], Hreg[r]);
    }
    __syncthreads();

    fft_pass<+1>(z, tid);   // exact inverse, output natural order, scaled by N (folded)

    // ---- store with fused residual ----
    const float Bd = Bg[d];
    float* y0 = y + (size_t)d * L_SEQ;
    float* y1 = y + (size_t)(D_MODEL + d) * L_SEQ;
#pragma unroll
    for (int r = 0; r < 8; ++r) {
        const int t = tid + r * NTH;
        const float2 v = z[SWZ(t)];
        y0[t] = v.x + x0[t] * Bd;
        y1[t] = v.y + x1[t] * Bd;
    }
}

extern "C" void kernel_launch(void* const* d_in, const int* in_sizes, int n_in,
                              void* d_out, int out_size, void* d_ws, size_t ws_size,
                              hipStream_t stream) {
    const float* h = (const float*)d_in[0];   // (1024, 8192)
    const float* x = (const float*)d_in[1];   // (2, 1024, 8192)
    const float* B = (const float*)d_in[2];   // (1024, 1)
    float* y = (float*)d_out;                 // (2, 1024, 8192)

    const size_t lds_bytes = (size_t)N_FFT * sizeof(float2);  // 128 KB

    fftconv_fused_kernel<<<dim3(D_MODEL), dim3(NTH), lds_bytes, stream>>>(h, x, B, y);
}

// Round 3
// 263.699 us; speedup vs baseline: 1.7440x; 1.1460x over previous
//
#include <hip/hip_runtime.h>
#include <hip/hip_bf16.h>

// FFTConv fused: y[b,d,:] = (h[d] (*) x[b,d])[0:L] + x[b,d]*B[d]
// d_model=1024, L=8192, batch=2, fp32. One 1024-thread block per channel.
// Radix-4 DIF forward (digit-reversed spectrum, never reordered), pointwise
// multiply fused in registers between the last forward stage and the first
// inverse stage (both have twiddle==1 and touch the same 4 elements), then
// stage-exact inverse -> natural-order output. Batch packed z = x0 + i*x1.
// Residual x*B folded into the spectrum: y = ifft(X*(H+B)/N).

#define L_SEQ   8192
#define N_FFT   16384
#define D_MODEL 1024
#define NTH     1024

// XOR swizzle on float2 index: caps LDS bank conflicts at ~4-way for all
// power-of-2 strides, keeps stride-1 access conflict-free.
#define SWZ(i) ((i) ^ (((i) >> 4) & 15))

__device__ __forceinline__ float2 cmul(float2 a, float2 b) {
    return make_float2(a.x * b.x - a.y * b.y, a.x * b.y + a.y * b.x);
}

// One LDS radix-4 stage (s in 0..5; stage 6 is done in registers by callers).
// SIGN=-1: forward DIF. SIGN=+1: exact inverse of the forward stage.
template <int SIGN>
__device__ __forceinline__ void fft_stage(float2* __restrict__ z, const int tid, const int s) {
    const int lq = 12 - 2 * s;       // log2(q), q = butterfly span
    const int q  = 1 << lq;
    const float fconst = (float)SIGN * 6.283185307179586f / (float)(1 << (lq + 2));
#pragma unroll
    for (int r = 0; r < 4; ++r) {
        const int t = tid + r * NTH;             // butterfly id 0..4095
        const int j = t & (q - 1);
        const int base = ((t >> lq) << (lq + 2)) | j;
        const int p0 = SWZ(base);
        const int p1 = SWZ(base + q);
        const int p2 = SWZ(base + 2 * q);
        const int p3 = SWZ(base + 3 * q);
        float sv, cv;
        __sincosf(fconst * (float)j, &sv, &cv);
        const float2 w1 = make_float2(cv, sv);
        const float2 w2 = cmul(w1, w1);
        const float2 w3 = cmul(w2, w1);
        if (SIGN < 0) {
            const float2 a0 = z[p0], a1 = z[p1], a2 = z[p2], a3 = z[p3];
            const float2 t0 = make_float2(a0.x + a2.x, a0.y + a2.y);
            const float2 t1 = make_float2(a0.x - a2.x, a0.y - a2.y);
            const float2 t2 = make_float2(a1.x + a3.x, a1.y + a3.y);
            const float2 t3 = make_float2(a1.x - a3.x, a1.y - a3.y);
            const float2 A0 = make_float2(t0.x + t2.x, t0.y + t2.y);
            const float2 A2 = make_float2(t0.x - t2.x, t0.y - t2.y);
            const float2 A1 = make_float2(t1.x + t3.y, t1.y - t3.x);   // t1 - i*t3
            const float2 A3 = make_float2(t1.x - t3.y, t1.y + t3.x);   // t1 + i*t3
            z[p0] = A0;
            z[p1] = cmul(A1, w1);
            z[p2] = cmul(A2, w2);
            z[p3] = cmul(A3, w3);
        } else {
            const float2 b0 = z[p0], b1 = z[p1], b2 = z[p2], b3 = z[p3];
            const float2 A0 = b0;
            const float2 A1 = cmul(b1, w1);   // w = conj(forward w) via SIGN
            const float2 A2 = cmul(b2, w2);
            const float2 A3 = cmul(b3, w3);
            const float2 u0 = make_float2(A0.x + A2.x, A0.y + A2.y);
            const float2 u1 = make_float2(A0.x - A2.x, A0.y - A2.y);
            const float2 u2 = make_float2(A1.x + A3.x, A1.y + A3.y);
            const float2 u3 = make_float2(A1.x - A3.x, A1.y - A3.y);
            z[p0] = make_float2(u0.x + u2.x, u0.y + u2.y);
            z[p2] = make_float2(u0.x - u2.x, u0.y - u2.y);
            z[p1] = make_float2(u1.x - u3.y, u1.y + u3.x);             // u1 + i*u3
            z[p3] = make_float2(u1.x + u3.y, u1.y - u3.x);             // u1 - i*u3
        }
    }
    __syncthreads();
}

__global__ void __launch_bounds__(NTH, 4) fftconv_fused_kernel(
        const float* __restrict__ h, const float* __restrict__ x,
        const float* __restrict__ Bg, float* __restrict__ y) {
    extern __shared__ float2 z[];
    const int d = blockIdx.x;
    const int tid = threadIdx.x;

    const float invn = 1.0f / (float)N_FFT;
    const float Bscaled = Bg[d] * invn;

    // ---- load + FFT of filter row (6 LDS stages; stage 7 captured in regs) ----
    const float* hrow = h + (size_t)d * L_SEQ;
#pragma unroll
    for (int r = 0; r < 8; ++r) {
        const int t = tid + r * NTH;
        z[SWZ(t)]         = make_float2(hrow[t], 0.0f);
        z[SWZ(t + L_SEQ)] = make_float2(0.0f, 0.0f);
    }
    __syncthreads();
#pragma unroll
    for (int s = 0; s < 6; ++s) fft_stage<-1>(z, tid, s);

    // final forward stage (q=1, twiddle==1) in registers -> Hreg = (H + B)/N
    float2 Hreg[16];
#pragma unroll
    for (int r = 0; r < 4; ++r) {
        const int b = 4 * (tid + r * NTH);
        const float2 a0 = z[SWZ(b)], a1 = z[SWZ(b + 1)], a2 = z[SWZ(b + 2)], a3 = z[SWZ(b + 3)];
        const float2 t0 = make_float2(a0.x + a2.x, a0.y + a2.y);
        const float2 t1 = make_float2(a0.x - a2.x, a0.y - a2.y);
        const float2 t2 = make_float2(a1.x + a3.x, a1.y + a3.y);
        const float2 t3 = make_float2(a1.x - a3.x, a1.y - a3.y);
        Hreg[4 * r + 0] = make_float2((t0.x + t2.x) * invn + Bscaled, (t0.y + t2.y) * invn);
        Hreg[4 * r + 1] = make_float2((t1.x + t3.y) * invn + Bscaled, (t1.y - t3.x) * invn);
        Hreg[4 * r + 2] = make_float2((t0.x - t2.x) * invn + Bscaled, (t0.y - t2.y) * invn);
        Hreg[4 * r + 3] = make_float2((t1.x - t3.y) * invn + Bscaled, (t1.y + t3.x) * invn);
    }
    __syncthreads();   // all stage-6 reads done before z is overwritten

    // ---- load + FFT of batch-packed signal z = x0 + i*x1 ----
    const float* x0 = x + (size_t)d * L_SEQ;
    const float* x1 = x + (size_t)(D_MODEL + d) * L_SEQ;
#pragma unroll
    for (int r = 0; r < 8; ++r) {
        const int t = tid + r * NTH;
        z[SWZ(t)]         = make_float2(x0[t], x1[t]);
        z[SWZ(t + L_SEQ)] = make_float2(0.0f, 0.0f);
    }
    __syncthreads();
#pragma unroll
    for (int s = 0; s < 6; ++s) fft_stage<-1>(z, tid, s);

    // ---- fused middle in registers: fwd stage 7 -> pointwise -> inv stage 1 ----
#pragma unroll
    for (int r = 0; r < 4; ++r) {
        const int b = 4 * (tid + r * NTH);
        const int p0 = SWZ(b), p1 = SWZ(b + 1), p2 = SWZ(b + 2), p3 = SWZ(b + 3);
        const float2 a0 = z[p0], a1 = z[p1], a2 = z[p2], a3 = z[p3];
        // forward radix-4 (w == 1)
        const float2 t0 = make_float2(a0.x + a2.x, a0.y + a2.y);
        const float2 t1 = make_float2(a0.x - a2.x, a0.y - a2.y);
        const float2 t2 = make_float2(a1.x + a3.x, a1.y + a3.y);
        const float2 t3 = make_float2(a1.x - a3.x, a1.y - a3.y);
        const float2 A0 = make_float2(t0.x + t2.x, t0.y + t2.y);
        const float2 A2 = make_float2(t0.x - t2.x, t0.y - t2.y);
        const float2 A1 = make_float2(t1.x + t3.y, t1.y - t3.x);
        const float2 A3 = make_float2(t1.x - t3.y, t1.y + t3.x);
        // pointwise multiply with (H+B)/N
        const float2 P0 = cmul(A0, Hreg[4 * r + 0]);
        const float2 P1 = cmul(A1, Hreg[4 * r + 1]);
        const float2 P2 = cmul(A2, Hreg[4 * r + 2]);
        const float2 P3 = cmul(A3, Hreg[4 * r + 3]);
        // inverse radix-4 (w == 1)
        const float2 u0 = make_float2(P0.x + P2.x, P0.y + P2.y);
        const float2 u1 = make_float2(P0.x - P2.x, P0.y - P2.y);
        const float2 u2 = make_float2(P1.x + P3.x, P1.y + P3.y);
        const float2 u3 = make_float2(P1.x - P3.x, P1.y - P3.y);
        z[p0] = make_float2(u0.x + u2.x, u0.y + u2.y);
        z[p2] = make_float2(u0.x - u2.x, u0.y - u2.y);
        z[p1] = make_float2(u1.x - u3.y, u1.y + u3.x);
        z[p3] = make_float2(u1.x + u3.y, u1.y - u3.x);
    }
    __syncthreads();

    // ---- remaining 6 inverse stages (s = 5 .. 0) ----
#pragma unroll
    for (int si = 0; si < 6; ++si) fft_stage<+1>(z, tid, 5 - si);

    // ---- store (residual already folded via spectrum) ----
    float* y0 = y + (size_t)d * L_SEQ;
    float* y1 = y + (size_t)(D_MODEL + d) * L_SEQ;
#pragma unroll
    for (int r = 0; r < 8; ++r) {
        const int t = tid + r * NTH;
        const float2 v = z[SWZ(t)];
        y0[t] = v.x;
        y1[t] = v.y;
    }
}

extern "C" void kernel_launch(void* const* d_in, const int* in_sizes, int n_in,
                              void* d_out, int out_size, void* d_ws, size_t ws_size,
                              hipStream_t stream) {
    const float* h = (const float*)d_in[0];   // (1024, 8192)
    const float* x = (const float*)d_in[1];   // (2, 1024, 8192)
    const float* B = (const float*)d_in[2];   // (1024, 1)
    float* y = (float*)d_out;                 // (2, 1024, 8192)

    const size_t lds_bytes = (size_t)N_FFT * sizeof(float2);  // 128 KB

    fftconv_fused_kernel<<<dim3(D_MODEL), dim3(NTH), lds_bytes, stream>>>(h, x, B, y);
}